// Round 7
// baseline (135.425 us; speedup 1.0000x reference)
//
#include <hip/hip_runtime.h>
#include <hip/hip_bf16.h>
#include <math.h>

// ---------------------------------------------------------------------------
// Problem shapes
// ---------------------------------------------------------------------------
#define NN 400000
#define GG 1024
#define E1 7
#define E2 70
#define E3 300

// Output layout (flat f32)
#define OFF_L1 0
#define OFF_L2 7168
#define OFF_L3 78848
#define OFF_P1 386048
#define OFF_G  393216

typedef float f32x4 __attribute__((ext_vector_type(4)));

__device__ __forceinline__ float gelu_exact(float v) {
  return 0.5f * v * (1.0f + erff(v * 0.70710678118654752f));
}

// ---------------------------------------------------------------------------
// ONE fused kernel, 1 graph per block (1024 blocks = 4 blocks/CU,
// 16 waves/CU -> 2x in-flight HBM bytes vs R6's 512 blocks).
//   Phase A: bounds via binary search (bidx sorted).
//   Phase B: segment mean, nt streaming loads, unroll-8 float4.
//   Phase C: MLP cascade on the block's single row; split-K keeps all
//            256 threads busy on the 128-wide hidden layers.
// ---------------------------------------------------------------------------
__global__ __launch_bounds__(256) void fused_kernel(
    const float* __restrict__ emb, const int* __restrict__ bidx,
    const float* __restrict__ pool_w, const float* __restrict__ pool_b,
    const float* __restrict__ w11, const float* __restrict__ b11,
    const float* __restrict__ w12, const float* __restrict__ b12,
    const float* __restrict__ w21, const float* __restrict__ b21,
    const float* __restrict__ w22, const float* __restrict__ b22,
    const float* __restrict__ w31, const float* __restrict__ b31,
    const float* __restrict__ w32, const float* __restrict__ b32,
    float* __restrict__ out) {
  const int g = blockIdx.x;
  const int tid = threadIdx.x;
  const int wave = tid >> 6, lane = tid & 63;

  __shared__ int seg[2];
  __shared__ float xs[336];      // concat activations: g | p1 | p2 (K=333)
  __shared__ float hs[128];      // hidden
  __shared__ float hpart[2][128];// split-K partials
  __shared__ float os[72];       // head logits (up to E2) for softmax
  __shared__ f32x4 red[4][64];   // cross-wave reduction

  // ---- Phase A: segment bounds ----
  if (tid < 2) {
    const int target = g + tid;
    int lo = 0, hi = NN;
    while (lo < hi) {
      int mid = (lo + hi) >> 1;
      if (bidx[mid] < target) lo = mid + 1; else hi = mid;
    }
    seg[tid] = lo;
  }
  __syncthreads();

  // ---- Phase B: segment mean (nt streaming loads) ----
  {
    const int start = seg[0], end = seg[1];
    const int hn = end - start;
    const int q0 = start + (hn * wave) / 4;
    const int q1 = start + (hn * (wave + 1)) / 4;
    const f32x4* __restrict__ p = (const f32x4*)emb + (size_t)q0 * 64 + lane;
    int n = q1 - q0;

    f32x4 a0 = {0.f, 0.f, 0.f, 0.f};
    f32x4 a1 = a0, a2 = a0, a3 = a0, a4 = a0, a5 = a0, a6 = a0, a7 = a0;
    for (; n >= 8; n -= 8, p += 512) {
      f32x4 v0 = __builtin_nontemporal_load(p + 0);
      f32x4 v1 = __builtin_nontemporal_load(p + 64);
      f32x4 v2 = __builtin_nontemporal_load(p + 128);
      f32x4 v3 = __builtin_nontemporal_load(p + 192);
      f32x4 v4 = __builtin_nontemporal_load(p + 256);
      f32x4 v5 = __builtin_nontemporal_load(p + 320);
      f32x4 v6 = __builtin_nontemporal_load(p + 384);
      f32x4 v7 = __builtin_nontemporal_load(p + 448);
      a0 += v0; a1 += v1; a2 += v2; a3 += v3;
      a4 += v4; a5 += v5; a6 += v6; a7 += v7;
    }
    for (; n > 0; --n, p += 64) {
      a0 += __builtin_nontemporal_load(p);
    }
    a0 += a1; a2 += a3; a4 += a5; a6 += a7;
    a0 += a2; a4 += a6;
    a0 += a4;

    red[wave][lane] = a0;
    __syncthreads();
    if (tid < 64) {
      f32x4 s = ((red[0][tid] + red[1][tid]) + (red[2][tid] + red[3][tid]));
      const float inv = 1.0f / (float)max(hn, 1);
      s *= inv;
      xs[4 * tid + 0] = s.x;
      xs[4 * tid + 1] = s.y;
      xs[4 * tid + 2] = s.z;
      xs[4 * tid + 3] = s.w;
    }
    __syncthreads();
  }

  // ---- Phase C1: pool  g = gelu(mean @ pool_w + pool_b) ----
  {
    const int j = tid;
    float a0 = 0.f;
#pragma unroll 8
    for (int k = 0; k < 256; ++k) a0 += xs[k] * pool_w[k * 256 + j];
    a0 = gelu_exact(a0 + pool_b[j]);
    __syncthreads();  // reads of xs (mean) complete before overwrite
    xs[j] = a0;
    out[OFF_G + g * 256 + j] = a0;
  }
  __syncthreads();

  // ---- Phase C2: ec1 hidden (K=256, split-K over 2 half-blocks) ----
  {
    const int half = tid >> 7, j = tid & 127;
    const int k0 = half * 128, k1 = k0 + 128;
    float a = 0.f;
#pragma unroll 8
    for (int k = k0; k < k1; ++k) a += xs[k] * w11[k * 128 + j];
    hpart[half][j] = a;
  }
  __syncthreads();
  if (tid < 128) hs[tid] = gelu_exact(hpart[0][tid] + hpart[1][tid] + b11[tid]);
  __syncthreads();
  // ec1 logits + softmax
  if (tid < E1) {
    float acc = b12[tid];
#pragma unroll 8
    for (int k = 0; k < 128; ++k) acc += hs[k] * w12[k * E1 + tid];
    os[tid] = acc;
    out[OFF_L1 + g * E1 + tid] = acc;
  }
  __syncthreads();
  if (tid == 0) {
    float m = os[0];
    for (int q = 1; q < E1; ++q) m = fmaxf(m, os[q]);
    float s = 0.f;
    for (int q = 0; q < E1; ++q) { float e = expf(os[q] - m); os[q] = e; s += e; }
    const float inv = 1.0f / s;
    for (int q = 0; q < E1; ++q) os[q] *= inv;
  }
  __syncthreads();
  if (tid < E1) {
    const float v = os[tid];
    out[OFF_P1 + g * E1 + tid] = v;
    xs[256 + tid] = v;  // append p1
  }
  __syncthreads();

  // ---- Phase C3: ec2 hidden (K=263, split-K) ----
  {
    const int K1 = 256 + E1;  // 263
    const int half = tid >> 7, j = tid & 127;
    const int k0 = (K1 * half) / 2, k1 = (K1 * (half + 1)) / 2;
    float a = 0.f;
#pragma unroll 8
    for (int k = k0; k < k1; ++k) a += xs[k] * w21[k * 128 + j];
    hpart[half][j] = a;
  }
  __syncthreads();
  if (tid < 128) hs[tid] = gelu_exact(hpart[0][tid] + hpart[1][tid] + b21[tid]);
  __syncthreads();
  if (tid < E2) {
    float acc = b22[tid];
#pragma unroll 8
    for (int k = 0; k < 128; ++k) acc += hs[k] * w22[k * E2 + tid];
    os[tid] = acc;
    out[OFF_L2 + g * E2 + tid] = acc;
  }
  __syncthreads();
  if (tid == 0) {
    float m = os[0];
    for (int q = 1; q < E2; ++q) m = fmaxf(m, os[q]);
    float s = 0.f;
    for (int q = 0; q < E2; ++q) { float e = expf(os[q] - m); os[q] = e; s += e; }
    const float inv = 1.0f / s;
    for (int q = 0; q < E2; ++q) os[q] *= inv;
  }
  __syncthreads();
  if (tid < E2) xs[256 + E1 + tid] = os[tid];  // append p2
  __syncthreads();

  // ---- Phase C4: ec3 hidden (K=333, split-K) ----
  {
    const int K1 = 256 + E1 + E2;  // 333
    const int half = tid >> 7, j = tid & 127;
    const int k0 = (K1 * half) / 2, k1 = (K1 * (half + 1)) / 2;
    float a = 0.f;
#pragma unroll 8
    for (int k = k0; k < k1; ++k) a += xs[k] * w31[k * 128 + j];
    hpart[half][j] = a;
  }
  __syncthreads();
  if (tid < 128) hs[tid] = gelu_exact(hpart[0][tid] + hpart[1][tid] + b31[tid]);
  __syncthreads();
  // ec3 logits straight to global
  for (int j = tid; j < E3; j += 256) {
    float acc = b32[j];
#pragma unroll 8
    for (int k = 0; k < 128; ++k) acc += hs[k] * w32[k * E3 + j];
    out[OFF_L3 + g * E3 + j] = acc;
  }
}

// ---------------------------------------------------------------------------
extern "C" void kernel_launch(void* const* d_in, const int* in_sizes, int n_in,
                              void* d_out, int out_size, void* d_ws, size_t ws_size,
                              hipStream_t stream) {
  const float* emb    = (const float*)d_in[0];
  const int*   bidx   = (const int*)d_in[1];
  const float* pool_w = (const float*)d_in[2];
  const float* pool_b = (const float*)d_in[3];
  const float* w11    = (const float*)d_in[4];
  const float* b11    = (const float*)d_in[5];
  const float* w12    = (const float*)d_in[6];
  const float* b12    = (const float*)d_in[7];
  const float* w21    = (const float*)d_in[8];
  const float* b21    = (const float*)d_in[9];
  const float* w22    = (const float*)d_in[10];
  const float* b22    = (const float*)d_in[11];
  const float* w31    = (const float*)d_in[12];
  const float* b31    = (const float*)d_in[13];
  const float* w32    = (const float*)d_in[14];
  const float* b32    = (const float*)d_in[15];
  float* out = (float*)d_out;

  fused_kernel<<<GG, 256, 0, stream>>>(
      emb, bidx, pool_w, pool_b, w11, b11, w12, b12,
      w21, b21, w22, b22, w31, b31, w32, b32, out);
}

// Round 8
// 105.778 us; speedup vs baseline: 1.2803x; 1.2803x over previous
//
#include <hip/hip_runtime.h>
#include <hip/hip_bf16.h>
#include <math.h>

// ---------------------------------------------------------------------------
// Problem shapes
// ---------------------------------------------------------------------------
#define NN 400000
#define GG 1024
#define E1 7
#define E2 70
#define E3 300

// Output layout (flat f32)
#define OFF_L1 0
#define OFF_L2 7168
#define OFF_L3 78848
#define OFF_P1 386048
#define OFF_G  393216

typedef float f32x4 __attribute__((ext_vector_type(4)));

__device__ __forceinline__ float gelu_exact(float v) {
  return 0.5f * v * (1.0f + erff(v * 0.70710678118654752f));
}

// ---------------------------------------------------------------------------
// K1: segment mean ONLY — R6's phases A+B verbatim (512 blocks, 2 graphs
// per block, nt streaming loads, unroll-8). Writes means to ws.
// ---------------------------------------------------------------------------
__global__ __launch_bounds__(256) void seg_mean_kernel(
    const float* __restrict__ emb, const int* __restrict__ bidx,
    float* __restrict__ gfm) {
  const int g0 = blockIdx.x * 2;
  const int tid = threadIdx.x;
  const int wave = tid >> 6, lane = tid & 63;

  __shared__ int seg[3];
  __shared__ f32x4 red[4][64];

  if (tid < 3) {
    const int target = g0 + tid;
    int lo = 0, hi = NN;
    while (lo < hi) {
      int mid = (lo + hi) >> 1;
      if (bidx[mid] < target) lo = mid + 1; else hi = mid;
    }
    seg[tid] = lo;
  }
  __syncthreads();

  for (int gg = 0; gg < 2; ++gg) {
    const int start = seg[gg], end = seg[gg + 1];
    const int hn = end - start;
    const int q0 = start + (hn * wave) / 4;
    const int q1 = start + (hn * (wave + 1)) / 4;
    const f32x4* __restrict__ p = (const f32x4*)emb + (size_t)q0 * 64 + lane;
    int n = q1 - q0;

    f32x4 a0 = {0.f, 0.f, 0.f, 0.f};
    f32x4 a1 = a0, a2 = a0, a3 = a0, a4 = a0, a5 = a0, a6 = a0, a7 = a0;
    for (; n >= 8; n -= 8, p += 512) {
      f32x4 v0 = __builtin_nontemporal_load(p + 0);
      f32x4 v1 = __builtin_nontemporal_load(p + 64);
      f32x4 v2 = __builtin_nontemporal_load(p + 128);
      f32x4 v3 = __builtin_nontemporal_load(p + 192);
      f32x4 v4 = __builtin_nontemporal_load(p + 256);
      f32x4 v5 = __builtin_nontemporal_load(p + 320);
      f32x4 v6 = __builtin_nontemporal_load(p + 384);
      f32x4 v7 = __builtin_nontemporal_load(p + 448);
      a0 += v0; a1 += v1; a2 += v2; a3 += v3;
      a4 += v4; a5 += v5; a6 += v6; a7 += v7;
    }
    for (; n > 0; --n, p += 64) {
      a0 += __builtin_nontemporal_load(p);
    }
    a0 += a1; a2 += a3; a4 += a5; a6 += a7;
    a0 += a2; a4 += a6;
    a0 += a4;

    red[wave][lane] = a0;
    __syncthreads();
    if (tid < 64) {
      f32x4 s = ((red[0][tid] + red[1][tid]) + (red[2][tid] + red[3][tid]));
      const float inv = 1.0f / (float)max(hn, 1);
      s *= inv;
      ((f32x4*)gfm)[(size_t)(g0 + gg) * 64 + tid] = s;
    }
    __syncthreads();
  }
}

// ---------------------------------------------------------------------------
// K2: full MLP cascade. 256 blocks x 512 threads, R=4 rows/block.
// 2 waves/SIMD (TLP for L2 latency) + split-K everywhere (short chains,
// LDS partial combine) + unroll-8 (ILP).
// ---------------------------------------------------------------------------
#define RB 4

__global__ __launch_bounds__(512) void mlp_kernel(
    const float* __restrict__ gfm,
    const float* __restrict__ pool_w, const float* __restrict__ pool_b,
    const float* __restrict__ w11, const float* __restrict__ b11,
    const float* __restrict__ w12, const float* __restrict__ b12,
    const float* __restrict__ w21, const float* __restrict__ b21,
    const float* __restrict__ w22, const float* __restrict__ b22,
    const float* __restrict__ w31, const float* __restrict__ b31,
    const float* __restrict__ w32, const float* __restrict__ b32,
    float* __restrict__ out) {
  const int r0 = blockIdx.x * RB;
  const int t = threadIdx.x;

  __shared__ float xs[RB][336];   // concat activations per row
  __shared__ float sbuf[2048];    // split-K partials (reused per stage)
  __shared__ float hs[RB][128];   // hidden
  __shared__ float os[RB][72];    // head logits for softmax
  __shared__ float lp[8][32];     // ec1 logit partials

  // load means
  for (int idx = t; idx < RB * 256; idx += 512) {
    const int r = idx >> 8, j = idx & 255;
    xs[r][j] = gfm[(size_t)(r0 + r) * 256 + j];
  }
  __syncthreads();

  // ---- pool: g = gelu(mean @ pool_w + pool_b), split-K x2 ----
  {
    const int ks = t >> 8, j = t & 255;
    const int k0 = ks * 128, k1 = k0 + 128;
    float a0 = 0.f, a1 = 0.f, a2 = 0.f, a3 = 0.f;
#pragma unroll 8
    for (int k = k0; k < k1; ++k) {
      const float w = pool_w[k * 256 + j];
      a0 += xs[0][k] * w; a1 += xs[1][k] * w;
      a2 += xs[2][k] * w; a3 += xs[3][k] * w;
    }
    sbuf[ks * 1024 + 0 * 256 + j] = a0;
    sbuf[ks * 1024 + 1 * 256 + j] = a1;
    sbuf[ks * 1024 + 2 * 256 + j] = a2;
    sbuf[ks * 1024 + 3 * 256 + j] = a3;
  }
  __syncthreads();
  for (int idx = t; idx < RB * 256; idx += 512) {
    const int r = idx >> 8, j = idx & 255;
    const float v = gelu_exact(sbuf[r * 256 + j] + sbuf[1024 + r * 256 + j] + pool_b[j]);
    xs[r][j] = v;
    out[OFF_G + (size_t)(r0 + r) * 256 + j] = v;
  }
  __syncthreads();

  // ---- ec1 hidden: K=256, split-K x4 ----
  {
    const int ks = t >> 7, j = t & 127;
    const int k0 = ks * 64, k1 = k0 + 64;
    float a0 = 0.f, a1 = 0.f, a2 = 0.f, a3 = 0.f;
#pragma unroll 8
    for (int k = k0; k < k1; ++k) {
      const float w = w11[k * 128 + j];
      a0 += xs[0][k] * w; a1 += xs[1][k] * w;
      a2 += xs[2][k] * w; a3 += xs[3][k] * w;
    }
    sbuf[ks * 512 + 0 * 128 + j] = a0;
    sbuf[ks * 512 + 1 * 128 + j] = a1;
    sbuf[ks * 512 + 2 * 128 + j] = a2;
    sbuf[ks * 512 + 3 * 128 + j] = a3;
  }
  __syncthreads();
  {
    const int r = t >> 7, j = t & 127;
    hs[r][j] = gelu_exact(sbuf[r * 128 + j] + sbuf[512 + r * 128 + j] +
                          sbuf[1024 + r * 128 + j] + sbuf[1536 + r * 128 + j] + b11[j]);
  }
  __syncthreads();
  // ---- ec1 logits: K=128, 28 outputs, split-K x8 ----
  if (t < 256) {
    const int ks = t >> 5, sl = t & 31;
    if (sl < RB * E1) {
      const int r = sl / E1, j = sl - r * E1;
      const int k0 = ks * 16, k1 = k0 + 16;
      float a = 0.f;
#pragma unroll 8
      for (int k = k0; k < k1; ++k) a += hs[r][k] * w12[k * E1 + j];
      lp[ks][sl] = a;
    }
  }
  __syncthreads();
  if (t < RB * E1) {
    const int r = t / E1, j = t - r * E1;
    float acc = b12[j];
#pragma unroll
    for (int ks = 0; ks < 8; ++ks) acc += lp[ks][t];
    os[r][j] = acc;
    out[OFF_L1 + (size_t)(r0 + r) * E1 + j] = acc;
  }
  __syncthreads();
  if (t < RB) {
    float m = os[t][0];
    for (int q = 1; q < E1; ++q) m = fmaxf(m, os[t][q]);
    float s = 0.f;
    for (int q = 0; q < E1; ++q) { float e = expf(os[t][q] - m); os[t][q] = e; s += e; }
    const float inv = 1.0f / s;
    for (int q = 0; q < E1; ++q) os[t][q] *= inv;
  }
  __syncthreads();
  if (t < RB * E1) {
    const int r = t / E1, j = t - r * E1;
    const float v = os[r][j];
    out[OFF_P1 + (size_t)(r0 + r) * E1 + j] = v;
    xs[r][256 + j] = v;
  }
  __syncthreads();

  // ---- ec2 hidden: K=263, split-K x4 ----
  {
    const int K1 = 256 + E1;  // 263
    const int ks = t >> 7, j = t & 127;
    const int k0 = (K1 * ks) / 4, k1 = (K1 * (ks + 1)) / 4;
    float a0 = 0.f, a1 = 0.f, a2 = 0.f, a3 = 0.f;
#pragma unroll 8
    for (int k = k0; k < k1; ++k) {
      const float w = w21[k * 128 + j];
      a0 += xs[0][k] * w; a1 += xs[1][k] * w;
      a2 += xs[2][k] * w; a3 += xs[3][k] * w;
    }
    sbuf[ks * 512 + 0 * 128 + j] = a0;
    sbuf[ks * 512 + 1 * 128 + j] = a1;
    sbuf[ks * 512 + 2 * 128 + j] = a2;
    sbuf[ks * 512 + 3 * 128 + j] = a3;
  }
  __syncthreads();
  {
    const int r = t >> 7, j = t & 127;
    hs[r][j] = gelu_exact(sbuf[r * 128 + j] + sbuf[512 + r * 128 + j] +
                          sbuf[1024 + r * 128 + j] + sbuf[1536 + r * 128 + j] + b21[j]);
  }
  __syncthreads();
  // ---- ec2 logits: K=128, 280 outputs, one thread each ----
  if (t < RB * E2) {
    const int r = t / E2, j = t - r * E2;
    float acc = b22[j];
#pragma unroll 8
    for (int k = 0; k < 128; ++k) acc += hs[r][k] * w22[k * E2 + j];
    os[r][j] = acc;
    out[OFF_L2 + (size_t)(r0 + r) * E2 + j] = acc;
  }
  __syncthreads();
  if (t < RB) {
    float m = os[t][0];
    for (int q = 1; q < E2; ++q) m = fmaxf(m, os[t][q]);
    float s = 0.f;
    for (int q = 0; q < E2; ++q) { float e = expf(os[t][q] - m); os[t][q] = e; s += e; }
    const float inv = 1.0f / s;
    for (int q = 0; q < E2; ++q) os[t][q] *= inv;
  }
  __syncthreads();
  if (t < RB * E2) {
    const int r = t / E2, j = t - r * E2;
    xs[r][256 + E1 + j] = os[r][j];
  }
  __syncthreads();

  // ---- ec3 hidden: K=333, split-K x4 ----
  {
    const int K1 = 256 + E1 + E2;  // 333
    const int ks = t >> 7, j = t & 127;
    const int k0 = (K1 * ks) / 4, k1 = (K1 * (ks + 1)) / 4;
    float a0 = 0.f, a1 = 0.f, a2 = 0.f, a3 = 0.f;
#pragma unroll 8
    for (int k = k0; k < k1; ++k) {
      const float w = w31[k * 128 + j];
      a0 += xs[0][k] * w; a1 += xs[1][k] * w;
      a2 += xs[2][k] * w; a3 += xs[3][k] * w;
    }
    sbuf[ks * 512 + 0 * 128 + j] = a0;
    sbuf[ks * 512 + 1 * 128 + j] = a1;
    sbuf[ks * 512 + 2 * 128 + j] = a2;
    sbuf[ks * 512 + 3 * 128 + j] = a3;
  }
  __syncthreads();
  {
    const int r = t >> 7, j = t & 127;
    hs[r][j] = gelu_exact(sbuf[r * 128 + j] + sbuf[512 + r * 128 + j] +
                          sbuf[1024 + r * 128 + j] + sbuf[1536 + r * 128 + j] + b31[j]);
  }
  __syncthreads();
  // ---- ec3 logits: K=128, 1200 outputs, grid-stride ----
  for (int idx = t; idx < RB * E3; idx += 512) {
    const int r = idx / E3, j = idx - r * E3;
    float acc = b32[j];
#pragma unroll 8
    for (int k = 0; k < 128; ++k) acc += hs[r][k] * w32[k * E3 + j];
    out[OFF_L3 + (size_t)(r0 + r) * E3 + j] = acc;
  }
}

// ---------------------------------------------------------------------------
extern "C" void kernel_launch(void* const* d_in, const int* in_sizes, int n_in,
                              void* d_out, int out_size, void* d_ws, size_t ws_size,
                              hipStream_t stream) {
  const float* emb    = (const float*)d_in[0];
  const int*   bidx   = (const int*)d_in[1];
  const float* pool_w = (const float*)d_in[2];
  const float* pool_b = (const float*)d_in[3];
  const float* w11    = (const float*)d_in[4];
  const float* b11    = (const float*)d_in[5];
  const float* w12    = (const float*)d_in[6];
  const float* b12    = (const float*)d_in[7];
  const float* w21    = (const float*)d_in[8];
  const float* b21    = (const float*)d_in[9];
  const float* w22    = (const float*)d_in[10];
  const float* b22    = (const float*)d_in[11];
  const float* w31    = (const float*)d_in[12];
  const float* b31    = (const float*)d_in[13];
  const float* w32    = (const float*)d_in[14];
  const float* b32    = (const float*)d_in[15];
  float* out = (float*)d_out;
  float* gfm = (float*)d_ws;  // [1024][256] f32 = 1 MB

  seg_mean_kernel<<<GG / 2, 256, 0, stream>>>(emb, bidx, gfm);
  mlp_kernel<<<GG / RB, 512, 0, stream>>>(gfm, pool_w, pool_b,
                                          w11, b11, w12, b12,
                                          w21, b21, w22, b22,
                                          w31, b31, w32, b32, out);
}